// Round 9
// baseline (154.849 us; speedup 1.0000x reference)
//
#include <hip/hip_runtime.h>
#include <math.h>

// AdderNet fused forward v9: one image per block, TWO waves per image
// (output-channel split) -> 4096 blocks x 128 thr, 16 blocks/CU = 32 waves/CU
// (full occupancy), ghost-free LDS 8544 B, lean registers (no spill).
//
// q(v) = round((v+8)*1024) u16; |q(a)-q(w)| = 1024*|a-w| (+-1). Pad = q(0).
// Integer requant (exact): L1 q=max(10752-((S+2)>>2),8192)
//   L2 q=max(24832-((S+4)>>3),8192)   L3 q=max(26112-((S+8)>>4),8192)
//
// d_ws (uint words): QW1[96]@0      [o16][kh3][{(w0,w1),(w2,0)}]
//                    QW2[2304]@96   [m8][o32][pk9]  word=(w[o][2m][pk],w[o][2m+1][pk])
//                    QW3[2304]@2400 [m2 16][o16][pk9]
//                    QW4[720]@4704  [m8][o10][pk9]
//
// LDS (2136 words = 8544 B):
//  sA1[1352]: A1 8 ch-pair planes x 13x13; after stage 2: part[1024]@0,
//             A3[136]@1100 (stride 17), l4[40]@1240, logits(float)[10]@1280
//  sA2[784] : A2 16 ch-pair planes x 7x7
// Boundary taps: lane-constant clamped offsets + select to QPAD.

#if defined(__has_builtin)
#if __has_builtin(__builtin_amdgcn_sad_u16)
#define HAS_SAD 1
#endif
#endif

__device__ __forceinline__ unsigned sadu16(unsigned a, unsigned b, unsigned acc) {
#ifdef HAS_SAD
  return __builtin_amdgcn_sad_u16(a, b, acc);
#else
  int al = (int)(a & 0xFFFFu), ah = (int)(a >> 16);
  int bl = (int)(b & 0xFFFFu), bh = (int)(b >> 16);
  return acc + (unsigned)(al > bl ? al - bl : bl - al)
             + (unsigned)(ah > bh ? ah - bh : bh - ah);
#endif
}

__device__ __forceinline__ unsigned quant(float v) {
  return (unsigned)fmaf(v, 1024.0f, 8192.5f);  // v >= -8 by construction
}
__device__ __forceinline__ unsigned quantx(float v) {  // quant(v - 0.5)
  return (unsigned)fmaf(v, 1024.0f, 7680.5f);
}
__device__ __forceinline__ int imax(int a, int b) { return a > b ? a : b; }

#define QPAD 0x20002000u

// ---------------- weight prep: quantize + repack into d_ws ----------------
__global__ void adder_prep(const float* __restrict__ w1, const float* __restrict__ w2,
                           const float* __restrict__ w3, const float* __restrict__ w4,
                           unsigned* __restrict__ qw) {
  int k = blockIdx.x * 256 + threadIdx.x;
  if (k < 96) {
    int o = k / 6, r = k % 6, kh = r >> 1, h = r & 1;
    const float* p = w1 + o * 9 + kh * 3;
    qw[k] = h ? quant(p[2]) : (quant(p[0]) | (quant(p[1]) << 16));
  } else if (k < 2400) {
    int k2 = k - 96, m = k2 / 288, r = k2 % 288, o = r / 9, pk = r % 9;
    int s = o * 144 + 2 * m * 9 + pk;
    qw[k] = quant(w2[s]) | (quant(w2[s + 9]) << 16);
  } else if (k < 4704) {
    int k3 = k - 2400, m2 = k3 / 144, r = k3 % 144, o = r / 9, pk = r % 9;
    int s = o * 288 + 2 * m2 * 9 + pk;
    qw[k] = quant(w3[s]) | (quant(w3[s + 9]) << 16);
  } else if (k < 5424) {
    int k4 = k - 4704, m = k4 / 90, r = k4 % 90, o = r / 9, pk = r % 9;
    int s = o * 144 + 2 * m * 9 + pk;
    qw[k] = quant(w4[s]) | (quant(w4[s + 9]) << 16);
  }
}

__global__ __launch_bounds__(128, 8) void adder_main(
    const float* __restrict__ gx,
    const unsigned* __restrict__ qw,
    float* __restrict__ gout)
{
  __shared__ __align__(16) unsigned sA1[1352];
  __shared__ __align__(16) unsigned sA2[784];

  const int t = threadIdx.x;
  const int wave = t >> 6;                  // 0 or 1
  const int lane = t & 63;
  const int b = blockIdx.x;
  const float* img = gx + (size_t)b * 784;

  // ---------------- stage 1: L1 [16,13,13]; wave w -> op 4w..4w+3 ----------
  if (lane < 52) {
    const int i = lane >> 2, jq = lane & 3;  // output rows i, cols j=4jq+jj
    unsigned r[3][5], mw[3][4];
#pragma unroll
    for (int kh = 0; kh < 3; ++kh) {
      const float* rp = img + (2 * i + kh) * 28 + 8 * jq;
      float4 A = *(const float4*)(rp);
      float4 B = *(const float4*)(rp + 4);
      float2 C = *(const float2*)(rp + 8);
      r[kh][0] = quantx(A.x) | (quantx(A.y) << 16);
      r[kh][1] = quantx(A.z) | (quantx(A.w) << 16);
      r[kh][2] = quantx(B.x) | (quantx(B.y) << 16);
      r[kh][3] = quantx(B.z) | (quantx(B.w) << 16);
      r[kh][4] = quantx(C.x) | (quantx(C.y) << 16);
#pragma unroll
      for (int c = 0; c < 4; ++c) mw[kh][c] = r[kh][c + 1] & 0xFFFFu;
    }
#pragma unroll 1
    for (int opl = 0; opl < 4; ++opl) {     // local channel pairs
      const int op = wave * 4 + opl;
      const unsigned* w = qw + op * 12;     // uniform -> s_load
      unsigned a0[4], a1[4];
#pragma unroll
      for (int jj = 0; jj < 4; ++jj) { a0[jj] = 0u; a1[jj] = 0u; }
#pragma unroll
      for (int kh = 0; kh < 3; ++kh) {
        unsigned wa01 = w[kh * 2], wa2 = w[kh * 2 + 1];
        unsigned wb01 = w[6 + kh * 2], wb2 = w[6 + kh * 2 + 1];
#pragma unroll
        for (int jj = 0; jj < 4; ++jj) {
          a0[jj] = sadu16(r[kh][jj], wa01, a0[jj]);
          a0[jj] = sadu16(mw[kh][jj], wa2, a0[jj]);
          a1[jj] = sadu16(r[kh][jj], wb01, a1[jj]);
          a1[jj] = sadu16(mw[kh][jj], wb2, a1[jj]);
        }
      }
      unsigned* dst = sA1 + op * 169 + i * 13 + 4 * jq;
#pragma unroll
      for (int jj = 0; jj < 4; ++jj) {
        if (4 * jq + jj < 13) {
          int q0 = imax(10752 - (int)((a0[jj] + 2u) >> 2), 8192);
          int q1 = imax(10752 - (int)((a1[jj] + 2u) >> 2), 8192);
          dst[jj] = (unsigned)q0 | ((unsigned)q1 << 16);
        }
      }
    }
  }
  __syncthreads();

  // ---------------- stage 2: L2 [32,7,7]; wave w -> o 16w..16w+15 ----------
  if (lane < 49) {
    const int i = lane / 7, j = lane % 7;
    int ro[3], co[3];
    bool rv[3], cv[3];
#pragma unroll
    for (int k = 0; k < 3; ++k) {
      int r = 2 * i - 1 + k;
      rv[k] = (r >= 0) && (r < 13);
      ro[k] = rv[k] ? r * 13 : 0;
      int c = 2 * j - 1 + k;
      cv[k] = (c >= 0) && (c < 13);
      co[k] = cv[k] ? c : 0;
    }
    unsigned acc[16];
#pragma unroll
    for (int o = 0; o < 16; ++o) acc[o] = 0u;
    const unsigned* qw2 = qw + 96 + wave * 144;
#pragma unroll 1
    for (int m = 0; m < 8; ++m) {
      const unsigned* plane = sA1 + m * 169;
      unsigned p[3][3];
#pragma unroll
      for (int kh = 0; kh < 3; ++kh)
#pragma unroll
        for (int c = 0; c < 3; ++c) {
          unsigned v = plane[ro[kh] + co[c]];
          p[kh][c] = (rv[kh] && cv[c]) ? v : QPAD;
        }
      const unsigned* wm = qw2 + m * 288;   // uniform -> s_load
#pragma unroll
      for (int o = 0; o < 16; ++o) {
        const unsigned* w9 = wm + o * 9;
        unsigned a = acc[o];
#pragma unroll
        for (int kh = 0; kh < 3; ++kh)
#pragma unroll
          for (int c = 0; c < 3; ++c)
            a = sadu16(p[kh][c], w9[kh * 3 + c], a);
        acc[o] = a;
      }
    }
#pragma unroll
    for (int m2 = 0; m2 < 8; ++m2) {
      int q0 = imax(24832 - (int)((acc[2 * m2] + 4u) >> 3), 8192);
      int q1 = imax(24832 - (int)((acc[2 * m2 + 1] + 4u) >> 3), 8192);
      sA2[(wave * 8 + m2) * 49 + i * 7 + j] = (unsigned)q0 | ((unsigned)q1 << 16);
    }
  }
  __syncthreads();

  // ------ stage 3: L3 [16,4,4]; og=wave (o 8w..8w+7), mg4 channel split -----
  {
    const int pos = lane & 15, mg = lane >> 4;      // mg 0..3
    const int i = pos >> 2, j = pos & 3;
    int ro[3], co[3];
    bool rv[3], cv[3];
#pragma unroll
    for (int k = 0; k < 3; ++k) {
      int r = 2 * i - 1 + k;
      rv[k] = (r >= 0) && (r < 7);
      ro[k] = rv[k] ? r * 7 : 0;
      int c = 2 * j - 1 + k;
      cv[k] = (c >= 0) && (c < 7);
      co[k] = cv[k] ? c : 0;
    }
    unsigned acc[8];
#pragma unroll
    for (int o = 0; o < 8; ++o) acc[o] = 0u;
    const unsigned* qw3 = qw + 2400;
#pragma unroll 1
    for (int mm = 0; mm < 4; ++mm) {
      const int m2 = mg * 4 + mm;
      const unsigned* plane = sA2 + m2 * 49;
      unsigned p[3][3];
#pragma unroll
      for (int kh = 0; kh < 3; ++kh)
#pragma unroll
        for (int c = 0; c < 3; ++c) {
          unsigned v = plane[ro[kh] + co[c]];
          p[kh][c] = (rv[kh] && cv[c]) ? v : QPAD;
        }
      const unsigned* ws = qw3 + m2 * 144 + wave * 72;  // uniform -> s_load
#pragma unroll
      for (int oo = 0; oo < 8; ++oo) {
        const unsigned* w9 = ws + oo * 9;
        unsigned a = acc[oo];
#pragma unroll
        for (int kh = 0; kh < 3; ++kh)
#pragma unroll
          for (int c = 0; c < 3; ++c)
            a = sadu16(p[kh][c], w9[kh * 3 + c], a);
        acc[oo] = a;
      }
    }
    unsigned* pp = sA1 + t * 8;             // A1 dead; part[1024]@0
    *(uint4*)(pp)     = make_uint4(acc[0], acc[1], acc[2], acc[3]);
    *(uint4*)(pp + 4) = make_uint4(acc[4], acc[5], acc[6], acc[7]);
  }
  __syncthreads();

  // reduce mg-groups -> A3 pair words [m8][pos16] @ sA1[1100..], stride 17
  if (t < 16) {
    const int pos = t;
#pragma unroll
    for (int m = 0; m < 8; ++m) {
      const int og = m >> 2, oo = 2 * (m & 3);
      unsigned s0 = 0u, s1 = 0u;
#pragma unroll
      for (int mg = 0; mg < 4; ++mg) {
        const int base = (og * 64 + mg * 16 + pos) * 8;
        s0 += sA1[base + oo];
        s1 += sA1[base + oo + 1];
      }
      int q0 = imax(26112 - (int)((s0 + 8u) >> 4), 8192);
      int q1 = imax(26112 - (int)((s1 + 8u) >> 4), 8192);
      sA1[1100 + m * 17 + pos] = (unsigned)q0 | ((unsigned)q1 << 16);
    }
  }
  __syncthreads();

  // ---------------- stage 4: L4 + log_softmax ----------------
  if (t < 80) {
    const int o = t % 10, mq = t / 10;      // mq 0..7 -> one m each
    const unsigned* qw4 = qw + 4704;
    const unsigned* a3 = sA1 + 1100 + mq * 17;
    const unsigned* w9 = qw4 + (mq * 10 + o) * 9;  // per-lane vector loads
    unsigned acc = 0u;
#pragma unroll
    for (int kh = 0; kh < 3; ++kh)
#pragma unroll
      for (int kw = 0; kw < 3; ++kw)
        acc = sadu16(a3[kh * 4 + kw], w9[kh * 3 + kw], acc);
    sA1[1240 + t] = acc;
  }
  __syncthreads();
  if (t < 10) {
    unsigned s = 0u;
#pragma unroll
    for (int mq = 0; mq < 8; ++mq) s += sA1[1240 + mq * 10 + t];
    ((float*)sA1)[1280 + t] = -(float)s * (1.0f / 1024.0f);
  }
  __syncthreads();
  if (t < 10) {
    const float* lg = (const float*)sA1 + 1280;
    float mx = lg[0];
#pragma unroll
    for (int k = 1; k < 10; ++k) mx = fmaxf(mx, lg[k]);
    float sum = 0.0f;
#pragma unroll
    for (int k = 0; k < 10; ++k) sum += __expf(lg[k] - mx);
    gout[(size_t)b * 10 + t] = lg[t] - mx - __logf(sum);
  }
}

extern "C" void kernel_launch(void* const* d_in, const int* in_sizes, int n_in,
                              void* d_out, int out_size, void* d_ws, size_t ws_size,
                              hipStream_t stream) {
  const float* x  = (const float*)d_in[0];
  const float* w1 = (const float*)d_in[1];
  const float* w2 = (const float*)d_in[2];
  const float* w3 = (const float*)d_in[3];
  const float* w4 = (const float*)d_in[4];
  unsigned* qw = (unsigned*)d_ws;           // 5424 words = 21.7 KB
  float* out = (float*)d_out;
  adder_prep<<<22, 256, 0, stream>>>(w1, w2, w3, w4, qw);
  adder_main<<<4096, 128, 0, stream>>>(x, qw, out);
}

// Round 10
// 118.905 us; speedup vs baseline: 1.3023x; 1.3023x over previous
//
#include <hip/hip_runtime.h>
#include <math.h>

// AdderNet fused forward v10: o-outer weight streaming. Weights re-laid out
// [o][m][k] (72 contiguous words per output channel) so each o-iteration's
// s_load chunk fits in SGPRs and pipelines across iterations; activations
// preloaded once per stage into VGPRs (clamps paid once, not per m).
// One wave per image, 4096x64, ghost-free LDS 8544 B -> 16 blocks/CU.
//
// q(v) = round((v+8)*1024) u16; |q(a)-q(w)| = 1024*|a-w| (+-1). Pad = q(0).
// Integer requant (exact): L1 q=max(10752-((S+2)>>2),8192)
//   L2 q=max(24832-((S+4)>>3),8192)   L3 q=max(26112-((S+8)>>4),8192)
//
// d_ws (uint words): QW1 [96]@0     [o16][kh3][{(w0,w1),(w2,0)}]
//                    QW2P[2304]@96  [o32][m8][k9]   word=(w[o][2m][k],w[o][2m+1][k])
//                    QW3P[2304]@2400 [o16][m2 16][k9]
//                    QW4 [720]@4704 [m8][o10][k9]
//
// LDS (2136 words = 8544 B):
//  sA1[1352]: A1 8 ch-pair planes x 13x13; after stage 2: part[512]@0,
//             A3[136]@1100 (stride 17), l4[40]@1240, logits(float)[10]@1280
//  sA2[784] : A2 16 ch-pair planes x 7x7

#if defined(__has_builtin)
#if __has_builtin(__builtin_amdgcn_sad_u16)
#define HAS_SAD 1
#endif
#endif

__device__ __forceinline__ unsigned sadu16(unsigned a, unsigned b, unsigned acc) {
#ifdef HAS_SAD
  return __builtin_amdgcn_sad_u16(a, b, acc);
#else
  int al = (int)(a & 0xFFFFu), ah = (int)(a >> 16);
  int bl = (int)(b & 0xFFFFu), bh = (int)(b >> 16);
  return acc + (unsigned)(al > bl ? al - bl : bl - al)
             + (unsigned)(ah > bh ? ah - bh : bh - ah);
#endif
}

__device__ __forceinline__ unsigned quant(float v) {
  return (unsigned)fmaf(v, 1024.0f, 8192.5f);  // v >= -8 by construction
}
__device__ __forceinline__ unsigned quantx(float v) {  // quant(v - 0.5)
  return (unsigned)fmaf(v, 1024.0f, 7680.5f);
}
__device__ __forceinline__ int imax(int a, int b) { return a > b ? a : b; }

#define QPAD 0x20002000u

// ---------------- weight prep: quantize + repack into d_ws ----------------
__global__ void adder_prep(const float* __restrict__ w1, const float* __restrict__ w2,
                           const float* __restrict__ w3, const float* __restrict__ w4,
                           unsigned* __restrict__ qw) {
  int k = blockIdx.x * 256 + threadIdx.x;
  if (k < 96) {
    int o = k / 6, r = k % 6, kh = r >> 1, h = r & 1;
    const float* p = w1 + o * 9 + kh * 3;
    qw[k] = h ? quant(p[2]) : (quant(p[0]) | (quant(p[1]) << 16));
  } else if (k < 2400) {
    int k2 = k - 96, o = k2 / 72, r = k2 % 72, m = r / 9, pk = r % 9;
    int s = o * 144 + 2 * m * 9 + pk;
    qw[k] = quant(w2[s]) | (quant(w2[s + 9]) << 16);
  } else if (k < 4704) {
    int k3 = k - 2400, o = k3 / 144, r = k3 % 144, m2 = r / 9, pk = r % 9;
    int s = o * 288 + 2 * m2 * 9 + pk;
    qw[k] = quant(w3[s]) | (quant(w3[s + 9]) << 16);
  } else if (k < 5424) {
    int k4 = k - 4704, m = k4 / 90, r = k4 % 90, o = r / 9, pk = r % 9;
    int s = o * 144 + 2 * m * 9 + pk;
    qw[k] = quant(w4[s]) | (quant(w4[s + 9]) << 16);
  }
}

__global__ __launch_bounds__(64, 4) void adder_main(
    const float* __restrict__ gx,
    const unsigned* __restrict__ qw,
    float* __restrict__ gout)
{
  __shared__ __align__(16) unsigned sA1[1352];
  __shared__ __align__(16) unsigned sA2[784];

  const int t = threadIdx.x;
  const int b = blockIdx.x;
  const float* img = gx + (size_t)b * 784;

  // ---------------- stage 1: L1 [16,13,13], X straight from global ----------
  if (t < 52) {
    const int i = t >> 2, jq = t & 3;       // output rows i, cols j=4jq+jj
    unsigned r[3][5], mw[3][4];
#pragma unroll
    for (int kh = 0; kh < 3; ++kh) {
      const float* rp = img + (2 * i + kh) * 28 + 8 * jq;
      float4 A = *(const float4*)(rp);
      float4 B = *(const float4*)(rp + 4);
      float2 C = *(const float2*)(rp + 8);
      r[kh][0] = quantx(A.x) | (quantx(A.y) << 16);
      r[kh][1] = quantx(A.z) | (quantx(A.w) << 16);
      r[kh][2] = quantx(B.x) | (quantx(B.y) << 16);
      r[kh][3] = quantx(B.z) | (quantx(B.w) << 16);
      r[kh][4] = quantx(C.x) | (quantx(C.y) << 16);
#pragma unroll
      for (int c = 0; c < 4; ++c) mw[kh][c] = r[kh][c + 1] & 0xFFFFu;
    }
#pragma unroll 2
    for (int op = 0; op < 8; ++op) {        // output-channel pairs
      const unsigned* w = qw + op * 12;     // uniform -> s_load (12 words)
      unsigned a0[4], a1[4];
#pragma unroll
      for (int jj = 0; jj < 4; ++jj) { a0[jj] = 0u; a1[jj] = 0u; }
#pragma unroll
      for (int kh = 0; kh < 3; ++kh) {
        unsigned wa01 = w[kh * 2], wa2 = w[kh * 2 + 1];
        unsigned wb01 = w[6 + kh * 2], wb2 = w[6 + kh * 2 + 1];
#pragma unroll
        for (int jj = 0; jj < 4; ++jj) {
          a0[jj] = sadu16(r[kh][jj], wa01, a0[jj]);
          a0[jj] = sadu16(mw[kh][jj], wa2, a0[jj]);
          a1[jj] = sadu16(r[kh][jj], wb01, a1[jj]);
          a1[jj] = sadu16(mw[kh][jj], wb2, a1[jj]);
        }
      }
      unsigned* dst = sA1 + op * 169 + i * 13 + 4 * jq;
#pragma unroll
      for (int jj = 0; jj < 4; ++jj) {
        if (4 * jq + jj < 13) {
          int q0 = imax(10752 - (int)((a0[jj] + 2u) >> 2), 8192);
          int q1 = imax(10752 - (int)((a1[jj] + 2u) >> 2), 8192);
          dst[jj] = (unsigned)q0 | ((unsigned)q1 << 16);
        }
      }
    }
  }
  __syncthreads();

  // ------- stage 2: L2 [32,7,7], o-outer, acts preloaded in VGPRs ----------
  if (t < 49) {
    const int i = t / 7, j = t % 7;
    // clamped offsets computed once
    int off[9];
    bool val[9];
#pragma unroll
    for (int kh = 0; kh < 3; ++kh) {
      int rr = 2 * i - 1 + kh;
      bool rvv = (rr >= 0) && (rr < 13);
      int roo = rvv ? rr * 13 : 0;
#pragma unroll
      for (int c = 0; c < 3; ++c) {
        int cc = 2 * j - 1 + c;
        bool cvv = (cc >= 0) && (cc < 13);
        val[kh * 3 + c] = rvv && cvv;
        off[kh * 3 + c] = roo + (cvv ? cc : 0);
      }
    }
    // preload 8 plane-patches (72 words) once
    unsigned p[8][9];
#pragma unroll
    for (int m = 0; m < 8; ++m) {
      const unsigned* plane = sA1 + m * 169;
#pragma unroll
      for (int k = 0; k < 9; ++k) {
        unsigned v = plane[off[k]];
        p[m][k] = val[k] ? v : QPAD;
      }
    }
    // o-pair loop: 144 contiguous weight words per iteration, 4 SAD chains
#pragma unroll 2
    for (int o2 = 0; o2 < 16; ++o2) {
      const unsigned* w = qw + 96 + o2 * 144;   // [oA 72][oB 72]
      unsigned aA0 = 0u, aA1 = 0u, aB0 = 0u, aB1 = 0u;
#pragma unroll
      for (int m = 0; m < 4; ++m)
#pragma unroll
        for (int k = 0; k < 9; ++k) {
          aA0 = sadu16(p[m][k],     w[m * 9 + k],       aA0);
          aA1 = sadu16(p[m + 4][k], w[36 + m * 9 + k],  aA1);
          aB0 = sadu16(p[m][k],     w[72 + m * 9 + k],  aB0);
          aB1 = sadu16(p[m + 4][k], w[108 + m * 9 + k], aB1);
        }
      unsigned SA = aA0 + aA1, SB = aB0 + aB1;
      int q0 = imax(24832 - (int)((SA + 4u) >> 3), 8192);
      int q1 = imax(24832 - (int)((SB + 4u) >> 3), 8192);
      sA2[o2 * 49 + i * 7 + j] = (unsigned)q0 | ((unsigned)q1 << 16);
    }
  }
  __syncthreads();

  // ------- stage 3: L3 [16,4,4], o-outer; lanes = pos16 x og2 x mg2 --------
  {
    const int pos = t & 15, og = (t >> 4) & 1, mg = t >> 5;
    const int i = pos >> 2, j = pos & 3;
    int off[9];
    bool val[9];
#pragma unroll
    for (int kh = 0; kh < 3; ++kh) {
      int rr = 2 * i - 1 + kh;
      bool rvv = (rr >= 0) && (rr < 7);
      int roo = rvv ? rr * 7 : 0;
#pragma unroll
      for (int c = 0; c < 3; ++c) {
        int cc = 2 * j - 1 + c;
        bool cvv = (cc >= 0) && (cc < 7);
        val[kh * 3 + c] = rvv && cvv;
        off[kh * 3 + c] = roo + (cvv ? cc : 0);
      }
    }
    unsigned p[8][9];
#pragma unroll
    for (int mm = 0; mm < 8; ++mm) {
      const unsigned* plane = sA2 + (mg * 8 + mm) * 49;
#pragma unroll
      for (int k = 0; k < 9; ++k) {
        unsigned v = plane[off[k]];
        p[mm][k] = val[k] ? v : QPAD;
      }
    }
#pragma unroll 2
    for (int oo = 0; oo < 8; ++oo) {
      // 72 contiguous words: [o = og*8+oo][m2 = mg*8 .. mg*8+7][k]
      const unsigned* w = qw + 2400 + (og * 8 + oo) * 144 + mg * 72;
      unsigned a0 = 0u, a1 = 0u;
#pragma unroll
      for (int mm = 0; mm < 4; ++mm)
#pragma unroll
        for (int k = 0; k < 9; ++k) {
          a0 = sadu16(p[mm][k],     w[mm * 9 + k],      a0);
          a1 = sadu16(p[mm + 4][k], w[36 + mm * 9 + k], a1);
        }
      // partial @ sA1[(o*16+pos)*2 + mg], o = og*8+oo
      sA1[((og * 8 + oo) * 16 + pos) * 2 + mg] = a0 + a1;
    }
  }
  __syncthreads();

  // reduce mg-halves -> A3 pair words [m8][pos16] @ sA1[1100..], stride 17
  if (t < 16) {
    const int pos = t;
#pragma unroll
    for (int m = 0; m < 8; ++m) {
      const int b0 = (2 * m * 16 + pos) * 2;
      const int b1 = ((2 * m + 1) * 16 + pos) * 2;
      unsigned s0 = sA1[b0] + sA1[b0 + 1];
      unsigned s1 = sA1[b1] + sA1[b1 + 1];
      int q0 = imax(26112 - (int)((s0 + 8u) >> 4), 8192);
      int q1 = imax(26112 - (int)((s1 + 8u) >> 4), 8192);
      sA1[1100 + m * 17 + pos] = (unsigned)q0 | ((unsigned)q1 << 16);
    }
  }
  __syncthreads();

  // ---------------- stage 4: L4 + log_softmax ----------------
  if (t < 40) {
    const int o = t % 10, mq = t / 10;
    const unsigned* qw4 = qw + 4704;
    unsigned acc = 0u;
#pragma unroll
    for (int mm = 0; mm < 2; ++mm) {
      const int m = mq * 2 + mm;
      const unsigned* a3 = sA1 + 1100 + m * 17;
      const unsigned* w9 = qw4 + (m * 10 + o) * 9;  // per-lane -> vector loads
#pragma unroll
      for (int kh = 0; kh < 3; ++kh)
#pragma unroll
        for (int kw = 0; kw < 3; ++kw)
          acc = sadu16(a3[kh * 4 + kw], w9[kh * 3 + kw], acc);
    }
    sA1[1240 + t] = acc;
  }
  __syncthreads();
  if (t < 10) {
    unsigned s = sA1[1240 + t] + sA1[1250 + t] + sA1[1260 + t] + sA1[1270 + t];
    ((float*)sA1)[1280 + t] = -(float)s * (1.0f / 1024.0f);
  }
  __syncthreads();
  if (t < 10) {
    const float* lg = (const float*)sA1 + 1280;
    float mx = lg[0];
#pragma unroll
    for (int k = 1; k < 10; ++k) mx = fmaxf(mx, lg[k]);
    float sum = 0.0f;
#pragma unroll
    for (int k = 0; k < 10; ++k) sum += __expf(lg[k] - mx);
    gout[(size_t)b * 10 + t] = lg[t] - mx - __logf(sum);
  }
}

extern "C" void kernel_launch(void* const* d_in, const int* in_sizes, int n_in,
                              void* d_out, int out_size, void* d_ws, size_t ws_size,
                              hipStream_t stream) {
  const float* x  = (const float*)d_in[0];
  const float* w1 = (const float*)d_in[1];
  const float* w2 = (const float*)d_in[2];
  const float* w3 = (const float*)d_in[3];
  const float* w4 = (const float*)d_in[4];
  unsigned* qw = (unsigned*)d_ws;           // 5424 words = 21.7 KB
  float* out = (float*)d_out;
  adder_prep<<<22, 256, 0, stream>>>(w1, w2, w3, w4, qw);
  adder_main<<<4096, 64, 0, stream>>>(x, qw, out);
}